// Round 8
// baseline (64.446 us; speedup 1.0000x reference)
//
#include <hip/hip_runtime.h>
#include <hip/hip_bf16.h>
#include <math.h>

typedef __attribute__((ext_vector_type(8))) short short8;
typedef __attribute__((ext_vector_type(4))) float floatx4;

static __device__ __forceinline__ unsigned short bfbits(float f) {
    __hip_bfloat16 h = __float2bfloat16(f);
    unsigned short u;
    __builtin_memcpy(&u, &h, 2);
    return u;
}
static __device__ __forceinline__ unsigned pack2(float lo, float hi) {
    return (unsigned)bfbits(lo) | ((unsigned)bfbits(hi) << 16);
}

// ---- LDS strides (bank patterns verified in R6/R7) ----
#define SP_STR  136   // u16; A-tiles, b128 frag reads
#define SBN_STR 76    // u16; natural [a][j] spline tile, u16 column frag reads
#define SBB_STR 136   // u16; base bw tile [o][a] (aliases sBn), b128 frag reads
#define ST_STR  68    // fp32
#define SC_STR  132

// Single fused kernel, 3 blocks/CU (LDS ~51 KB).
// block (nb, s): rows [16nb,16nb+16), out cols [32s,32s+32).
// Spline chunks {s, s+4, s+8, s+12} (b-group = t), base = bw rows [32s,32s+32).
__global__ __launch_bounds__(256, 3) void kan_fused(
    const float* __restrict__ x,
    const float* __restrict__ bw,
    const float* __restrict__ sw,
    float* __restrict__ out)
{
    __shared__ short sP[5 * 16 * SP_STR];          // 21760 B
    __shared__ short sBn[128 * SBN_STR];           // 19456 B (also base tile)
    __shared__ float sT[2][16 * ST_STR];           //  8704 B
    __shared__ unsigned char sC[16 * SC_STR];      //  2112 B

    const int tid = threadIdx.x;
    const int nb  = blockIdx.x >> 2;
    const int s   = blockIdx.x & 3;
    const int n0  = nb * 16;

    const int ar = tid >> 4;          // staging: a-row base 0..15
    const int sg = tid & 15;          // staging: 16B segment within 64-col chunk

    // ---- x loads + chunk-0 half-0 prefetch (latency hides under basis VALU) ----
    const int r  = tid >> 4;
    const int i0 = (tid & 15) * 8;
    float v[8];
    *(float4*)(v)     = *(const float4*)(x + (n0 + r) * 128 + i0);
    *(float4*)(v + 4) = *(const float4*)(x + (n0 + r) * 128 + i0 + 4);

    float4 pre[4];
#pragma unroll
    for (int rr = 0; rr < 4; ++rr)
        pre[rr] = *(const float4*)(sw + (ar + 16 * rr) * 1024 + s * 64 + sg * 4);

    // ---- prologue: silu/u/c + basis for 16 rows x 128 feats ----
    {
        float A5[5][8];
        unsigned char cc8[8];
#pragma unroll
        for (int i = 0; i < 8; ++i) {
            float xv = v[i];
            float si = xv / (1.0f + expf(-xv));
            float xn = fminf(fmaxf(xv, -1.0f), 1.0f);
            float t  = (xn + 2.2f) / 0.4f;     // (xn - G0)/H, bit-exact vs verified path
            float u  = t - floorf(t);
            int idx  = (int)floorf(t);
            idx = min(max(idx, 3), 7);
            cc8[i] = (unsigned char)(idx - 3);
            float u2 = u * u, u3 = u2 * u, om = 1.0f - u;
            A5[0][i] = om * om * om * (1.0f / 6.0f);
            A5[1][i] = 0.5f * u3 - u2 + (2.0f / 3.0f);
            A5[2][i] = -0.5f * u3 + 0.5f * u2 + 0.5f * u + (1.0f / 6.0f);
            A5[3][i] = u3 * (1.0f / 6.0f);
            A5[4][i] = si;
        }
#pragma unroll
        for (int g = 0; g < 5; ++g) {
            unsigned p0 = pack2(A5[g][0], A5[g][1]);
            unsigned p1 = pack2(A5[g][2], A5[g][3]);
            unsigned p2 = pack2(A5[g][4], A5[g][5]);
            unsigned p3 = pack2(A5[g][6], A5[g][7]);
            *(uint4*)(&sP[(g * 16 + r) * SP_STR + i0]) = make_uint4(p0, p1, p2, p3);
        }
        *(unsigned*)(&sC[r * SC_STR + i0])     = cc8[0] | (cc8[1]<<8) | (cc8[2]<<16) | (cc8[3]<<24);
        *(unsigned*)(&sC[r * SC_STR + i0 + 4]) = cc8[4] | (cc8[5]<<8) | (cc8[6]<<16) | (cc8[7]<<24);
    }

    // ---- stage chunk 0: half 0 from pre, half 1 direct ----
#pragma unroll
    for (int rr = 0; rr < 4; ++rr)
        *(uint2*)(&sBn[(ar + 16 * rr) * SBN_STR + sg * 4]) =
            make_uint2(pack2(pre[rr].x, pre[rr].y), pack2(pre[rr].z, pre[rr].w));
#pragma unroll
    for (int rr = 4; rr < 8; ++rr) {
        float4 h = *(const float4*)(sw + (ar + 16 * rr) * 1024 + s * 64 + sg * 4);
        *(uint2*)(&sBn[(ar + 16 * rr) * SBN_STR + sg * 4]) =
            make_uint2(pack2(h.x, h.y), pack2(h.z, h.w));
    }
    __syncthreads();   // B(0): sBn chunk0 + sP + sC ready

    const int w = tid >> 6, l = tid & 63;
    const int m = l & 15, q = l >> 4;
    const int gn  = tid >> 4;         // gather/store: n row 0..15
    const int go2 = tid & 15;         // gather/store: o-pair
    const int oh  = 8 * s + (go2 >> 1);
    const int oloc = 8 * (go2 >> 1) + 2 * (go2 & 1);

    float racc0 = 0.f, racc1 = 0.f;
    float4 bpre[4];

#pragma unroll
    for (int t = 0; t < 4; ++t) {
        const int p = t & 1;

        // prefetch next chunk half-0 (or base bw tile at t=3)
        if (t < 3) {
#pragma unroll
            for (int rr = 0; rr < 4; ++rr)
                pre[rr] = *(const float4*)(sw + (ar + 16 * rr) * 1024 + (s + 4 * (t + 1)) * 64 + sg * 4);
        } else {
#pragma unroll
            for (int i = 0; i < 4; ++i) {
                int e = i * 256 + tid;
                bpre[i] = *(const float4*)(bw + (32 * s + (e >> 5)) * 128 + (e & 31) * 4);
            }
        }

        // gather chunk t-1 from sT[1-p] (ordered by the two barriers below)
        if (t > 0) {
            int c   = sC[gn * SC_STR + 32 * (t - 1) + oh];
            int rel = oloc + c;
            racc0 += sT[1 - p][gn * ST_STR + rel];
            racc1 += sT[1 - p][gn * ST_STR + rel + 1];
        }

        // MFMA chunk t: A = sP group t, B-frags via u16 column reads of natural tile
        floatx4 acc = {0.f, 0.f, 0.f, 0.f};
#pragma unroll
        for (int kk = 0; kk < 4; ++kk) {
            short8 af = *(const short8*)(&sP[(t * 16 + m) * SP_STR + q * 8 + kk * 32]);
            short8 bf;
#pragma unroll
            for (int j2 = 0; j2 < 8; ++j2)
                bf[j2] = sBn[(kk * 32 + q * 8 + j2) * SBN_STR + 16 * w + m];
            acc = __builtin_amdgcn_mfma_f32_16x16x32_bf16(af, bf, acc, 0, 0, 0);
        }
#pragma unroll
        for (int rr = 0; rr < 4; ++rr)
            sT[p][(q * 4 + rr) * ST_STR + 16 * w + m] = acc[rr];

        __syncthreads();   // A(t+1): frag reads of chunk t done -> sBn reusable; sT[p] visible

        // restage sBn: next spline chunk (half0 from pre, half1 direct) or base tile
        if (t < 3) {
#pragma unroll
            for (int rr = 0; rr < 4; ++rr)
                *(uint2*)(&sBn[(ar + 16 * rr) * SBN_STR + sg * 4]) =
                    make_uint2(pack2(pre[rr].x, pre[rr].y), pack2(pre[rr].z, pre[rr].w));
#pragma unroll
            for (int rr = 4; rr < 8; ++rr) {
                float4 h = *(const float4*)(sw + (ar + 16 * rr) * 1024 + (s + 4 * (t + 1)) * 64 + sg * 4);
                *(uint2*)(&sBn[(ar + 16 * rr) * SBN_STR + sg * 4]) =
                    make_uint2(pack2(h.x, h.y), pack2(h.z, h.w));
            }
        } else {
#pragma unroll
            for (int i = 0; i < 4; ++i) {
                int e = i * 256 + tid;
                *(uint2*)(&sBn[(e >> 5) * SBB_STR + (e & 31) * 4]) =
                    make_uint2(pack2(bpre[i].x, bpre[i].y), pack2(bpre[i].z, bpre[i].w));
            }
        }
        __syncthreads();   // B(t+1): sBn restaged
    }

    // ---- base MFMA (32 cols, waves 0,1) from aliased tile ----
    if (w < 2) {
        floatx4 acc = {0.f, 0.f, 0.f, 0.f};
#pragma unroll
        for (int kk = 0; kk < 4; ++kk) {
            short8 af = *(const short8*)(&sP[(4 * 16 + m) * SP_STR + q * 8 + kk * 32]);
            short8 bf = *(const short8*)(&sBn[(16 * w + m) * SBB_STR + q * 8 + kk * 32]);
            acc = __builtin_amdgcn_mfma_f32_16x16x32_bf16(af, bf, acc, 0, 0, 0);
        }
#pragma unroll
        for (int rr = 0; rr < 4; ++rr)
            sT[0][(q * 4 + rr) * ST_STR + 16 * w + m] = acc[rr];   // chunk2 gathers done (pre-A(4))
    }
    __syncthreads();

    // ---- final gathers: chunk 3 (sT[1]) + base (sT[0]); exclusive store ----
    {
        int c   = sC[gn * SC_STR + 32 * 3 + oh];
        int rel = oloc + c;
        racc0 += sT[1][gn * ST_STR + rel];
        racc1 += sT[1][gn * ST_STR + rel + 1];
    }
    racc0 += sT[0][gn * ST_STR + 2 * go2];
    racc1 += sT[0][gn * ST_STR + 2 * go2 + 1];

    *(float2*)(out + (n0 + gn) * 128 + 32 * s + 2 * go2) = make_float2(racc0, racc1);
}

extern "C" void kernel_launch(void* const* d_in, const int* in_sizes, int n_in,
                              void* d_out, int out_size, void* d_ws, size_t ws_size,
                              hipStream_t stream) {
    const float* x  = (const float*)d_in[0];
    const float* bw = (const float*)d_in[1];
    const float* sw = (const float*)d_in[2];
    float* out = (float*)d_out;
    kan_fused<<<dim3(512), dim3(256), 0, stream>>>(x, bw, sw, out);
}